// Round 19
// baseline (139.171 us; speedup 1.0000x reference)
//
#include <hip/hip_runtime.h>
#include <math.h>

#define EPSF 1e-12f

typedef short bf16x8 __attribute__((ext_vector_type(8)));
typedef float f32x4 __attribute__((ext_vector_type(4)));

__device__ __forceinline__ void gload_lds16(const void* g, void* l) {
  __builtin_amdgcn_global_load_lds(
      (const __attribute__((address_space(1))) unsigned int*)g,
      (__attribute__((address_space(3))) unsigned int*)l, 16, 0, 0);
}

__device__ __forceinline__ unsigned short bf16_rne(float f) {
  unsigned int u = __float_as_uint(f);
  u += 0x7fffu + ((u >> 16) & 1u);
  return (unsigned short)(u >> 16);
}

__device__ __forceinline__ float bf16_to_f32(unsigned short h) {
  return __uint_as_float((unsigned int)h << 16);
}

// ---------------- stage 1+2 FUSED: tgt readout (blocks 0..255) + src readout (256..1279) ----------------
#define WST 72
#define SMEM_BYTES 39424  // tgt path: Wb 18432 + omT 18432 + cntp 2048 + cnt_inv 512
__global__ __launch_bounds__(512) void k_readouts(
    const float* __restrict__ m, const int* __restrict__ src_mask,
    unsigned short* __restrict__ srcRb, float* __restrict__ ssq,
    const float* __restrict__ om, const int* __restrict__ tgt_mask,
    unsigned short* __restrict__ Afrag, float* __restrict__ tsqp) {
  __shared__ __attribute__((aligned(16))) char smem_raw[SMEM_BYTES];
  const int tid = threadIdx.x;

  if (blockIdx.x < 256) {
    // ---------------- tgt path ----------------
    const int b = blockIdx.x >> 3, dq = (blockIdx.x >> 1) & 3, th = blockIdx.x & 1;
    const int d0 = dq * 128, t0 = th * 128;
    unsigned short* Wb = (unsigned short*)smem_raw;
    unsigned short* omT = (unsigned short*)(smem_raw + 18432);
    float* cntp = (float*)(smem_raw + 36864);
    float* cnt_inv = (float*)(smem_raw + 38912);
    const int lane = tid & 63, w = tid >> 6;
    const int* mbase = tgt_mask + (size_t)b * 65536 + (size_t)t0 * 256;

    {
      const int t = tid >> 2, q = tid & 3;
      const int* mp = mbase + t * 256 + q * 64;
      int c = 0;
#pragma unroll
      for (int k = 0; k < 16; ++k) {
        int4 v = *(const int4*)(mp + 4 * k);
        c += v.x + v.y + v.z + v.w;
      }
      cntp[t * 4 + q] = (float)c;
    }
    __syncthreads();
    if (tid < 128) {
      float c = cntp[tid * 4] + cntp[tid * 4 + 1] + cntp[tid * 4 + 2] + cntp[tid * 4 + 3];
      cnt_inv[tid] = 1.0f / fmaxf(c, EPSF);
    }

    f32x4 acc[8];
#pragma unroll
    for (int di = 0; di < 8; ++di) acc[di] = (f32x4){0.f, 0.f, 0.f, 0.f};

    for (int uc = 0; uc < 4; ++uc) {
      const int ub = uc * 64;
      __syncthreads();
      {
        const int t = tid >> 2, ul0 = (tid & 3) * 16;
        const int* mp = mbase + t * 256 + ub + ul0;
        unsigned short* wp = Wb + t * WST + ul0;
#pragma unroll
        for (int k = 0; k < 4; ++k) {
          int4 v = *(const int4*)(mp + 4 * k);
          ushort4 h;
          h.x = v.x ? 0x3F80 : 0;
          h.y = v.y ? 0x3F80 : 0;
          h.z = v.z ? 0x3F80 : 0;
          h.w = v.w ? 0x3F80 : 0;
          *(ushort4*)(wp + 4 * k) = h;
        }
      }
      {
#pragma unroll
        for (int k = 0; k < 4; ++k) {
          const int idx = tid + 512 * k;
          const int u = idx >> 5, dl = (idx & 31) * 4;
          float4 v = *(const float4*)(om + (size_t)b * 131072 + (size_t)(ub + u) * 512 + d0 + dl);
          omT[(dl + 0) * WST + u] = bf16_rne(v.x);
          omT[(dl + 1) * WST + u] = bf16_rne(v.y);
          omT[(dl + 2) * WST + u] = bf16_rne(v.z);
          omT[(dl + 3) * WST + u] = bf16_rne(v.w);
        }
      }
      __syncthreads();
#pragma unroll
      for (int kt2 = 0; kt2 < 2; ++kt2) {
        const int ko = kt2 * 32 + (lane >> 4) * 8;
        bf16x8 wf = *(const bf16x8*)(Wb + (w * 16 + (lane & 15)) * WST + ko);
        bf16x8 of[8];
#pragma unroll
        for (int di = 0; di < 8; ++di)
          of[di] = *(const bf16x8*)(omT + (di * 16 + (lane & 15)) * WST + ko);
#pragma unroll
        for (int di = 0; di < 8; ++di)
          acc[di] = __builtin_amdgcn_mfma_f32_16x16x32_bf16(of[di], wf, acc[di], 0, 0, 0);
      }
    }

    const int tl = w * 16 + (lane & 15);
    const int rT = b * 256 + t0 + tl;
    const float inv = cnt_inv[tl];
    float sq = 0.f;
#pragma unroll
    for (int di = 0; di < 8; ++di) {
      const int d = d0 + di * 16 + (lane >> 4) * 4;
      ushort4 o;
      o.x = bf16_rne(acc[di][0] * inv);
      o.y = bf16_rne(acc[di][1] * inv);
      o.z = bf16_rne(acc[di][2] * inv);
      o.w = bf16_rne(acc[di][3] * inv);
      float fx = bf16_to_f32(o.x), fy = bf16_to_f32(o.y);
      float fz = bf16_to_f32(o.z), fw = bf16_to_f32(o.w);
      sq += fx * fx + fy * fy + fz * fz + fw * fw;
      const size_t off =
          (((size_t)(rT >> 4) * 16 + (d >> 5)) * 64 + ((d >> 3) & 3) * 16 + (rT & 15)) * 8 + (d & 7);
      *(ushort4*)(Afrag + off) = o;
    }
    sq += __shfl_xor(sq, 16, 64);
    sq += __shfl_xor(sq, 32, 64);
    if ((lane >> 4) == 0) tsqp[(size_t)dq * 8192 + rT] = sq;
  } else {
    // ---------------- src path: 4 batches per block ----------------
    const int sid = blockIdx.x - 256;
    const int sub = tid >> 7, t = tid & 127;
    const int b = sid * 4 + sub;
    int* msk = (int*)smem_raw;            // [4][32]
    float* sinv = (float*)(smem_raw + 512);
    float* red = (float*)(smem_raw + 528);  // [8]
    if (t < 32) msk[sub * 32 + t] = src_mask[b * 32 + t];
    __syncthreads();
    if (t == 0) {
      float c = 0.f;
      for (int s = 0; s < 32; ++s) c += (float)msk[sub * 32 + s];
      sinv[sub] = 1.0f / fmaxf(c, EPSF);
    }
    __syncthreads();
    const float inv = sinv[sub];
    const float4* mb = (const float4*)(m + (size_t)b * (32 * 512)) + t;
    float ax = 0.f, ay = 0.f, az = 0.f, aw = 0.f;
    for (int s = 0; s < 32; ++s) {
      if (msk[sub * 32 + s] != 0) {
        float4 v = mb[s * 128];
        ax += v.x; ay += v.y; az += v.z; aw += v.w;
      }
    }
    ushort4 o;
    o.x = bf16_rne(ax * inv);
    o.y = bf16_rne(ay * inv);
    o.z = bf16_rne(az * inv);
    o.w = bf16_rne(aw * inv);
    *(ushort4*)(srcRb + (size_t)b * 512 + t * 4) = o;
    float fx = bf16_to_f32(o.x), fy = bf16_to_f32(o.y);
    float fz = bf16_to_f32(o.z), fw = bf16_to_f32(o.w);
    float s = fx * fx + fy * fy + fz * fz + fw * fw;
#pragma unroll
    for (int oo = 32; oo > 0; oo >>= 1) s += __shfl_down(s, oo, 64);
    if ((tid & 63) == 0) red[tid >> 6] = s;
    __syncthreads();
    if (t == 0) ssq[b] = red[sub * 2] + red[sub * 2 + 1];
  }
}

// ---------------- stage 3: cross GEMM — 16 waves; epilogue uses v_cvt_pk_bf16_f32 ----------------
template <int BF16SIM>
__global__ __launch_bounds__(1024, 4) void k_cross_mfma(
    const unsigned short* __restrict__ Afrag, const unsigned short* __restrict__ B,
    const float* __restrict__ tsqp, const float* __restrict__ ssq,
    unsigned short* __restrict__ simU, float* __restrict__ psum,
    float* __restrict__ outF) {
  __shared__ unsigned short Bs[128 * 512];
  const int tid = threadIdx.x;
  const int lane = tid & 63, w = tid >> 6;  // 16 waves
  const int bid = blockIdx.x;
  const int xcd = bid & 7, idx = bid >> 3;
  const int row0 = (xcd * 2 + (idx >> 5)) * 512;
  const int col0 = (idx & 31) * 128;
  const int lr = lane & 15, lkh = lane >> 4;

#pragma unroll
  for (int t = 0; t < 8; ++t) {
    const int c = w * 8 + t;
    const int j = c >> 4, kt = c & 15;
    gload_lds16(B + (size_t)(col0 + j * 16 + lr) * 512 + kt * 32 + lkh * 8,
                Bs + (size_t)c * 512);
  }

  f32x4 acc[2][8];
#pragma unroll
  for (int i = 0; i < 2; ++i)
#pragma unroll
    for (int j = 0; j < 8; ++j) acc[i][j] = (f32x4){0.f, 0.f, 0.f, 0.f};

  __syncthreads();

  const unsigned short* ap = Afrag + ((size_t)(row0 >> 4) + w * 2) * (16 * 64 * 8);
#pragma unroll
  for (int kt = 0; kt < 16; ++kt) {
    bf16x8 af[2], bfr[8];
#pragma unroll
    for (int i = 0; i < 2; ++i)
      af[i] = *(const bf16x8*)(ap + (((size_t)i * 16 + kt) * 64 + lane) * 8);
#pragma unroll
    for (int j = 0; j < 8; ++j)
      bfr[j] = *(const bf16x8*)(Bs + ((j * 16 + kt) * 64 + lane) * 8);
#pragma unroll
    for (int i = 0; i < 2; ++i)
#pragma unroll
      for (int j = 0; j < 8; ++j)
        acc[i][j] = __builtin_amdgcn_mfma_f32_16x16x32_bf16(af[i], bfr[j], acc[i][j], 0, 0, 0);
  }

  const int cbase = col0 + (lane & 15);
  const int rbase = row0 + w * 32 + (lane >> 4) * 4;
  float ss[8];
#pragma unroll
  for (int j = 0; j < 8; ++j) ss[j] = ssq[cbase + j * 16];
#pragma unroll
  for (int i = 0; i < 2; ++i) {
#pragma unroll
    for (int r = 0; r < 4; ++r) {
      const int row = rbase + i * 16 + r;
      const float t2 = tsqp[row] + tsqp[8192 + row] + tsqp[2 * 8192 + row] + tsqp[3 * 8192 + row];
      if (BF16SIM) {
        unsigned short* sp = simU + (size_t)row * 4096 + cbase;
        float simv[8];
        float s = 0.f;
#pragma unroll
        for (int j = 0; j < 8; ++j) {
          float d2 = t2 + ss[j] - 2.0f * acc[i][j][r];
          float sim = __expf(-__builtin_amdgcn_sqrtf(fmaxf(d2, EPSF)));
          s += sim;
          simv[j] = sim;
        }
        // pack pairs with HW RNE converter (T12 recipe: %1 -> low16, %2 -> high16)
#pragma unroll
        for (int p = 0; p < 4; ++p) {
          unsigned int pk;
          asm("v_cvt_pk_bf16_f32 %0, %1, %2"
              : "=v"(pk)
              : "v"(simv[2 * p]), "v"(simv[2 * p + 1]));
          __builtin_nontemporal_store((unsigned short)(pk & 0xffffu), sp + (2 * p) * 16);
          __builtin_nontemporal_store((unsigned short)(pk >> 16), sp + (2 * p + 1) * 16);
        }
        s += __shfl_xor(s, 1, 64);
        s += __shfl_xor(s, 2, 64);
        s += __shfl_xor(s, 4, 64);
        s += __shfl_xor(s, 8, 64);
        if ((lane & 15) == 0) psum[(size_t)row * 32 + (col0 >> 7)] = s;
      } else {
        float* op = outF + (size_t)row * 4096 + cbase;
#pragma unroll
        for (int j = 0; j < 8; ++j) {
          float d2 = t2 + ss[j] - 2.0f * acc[i][j][r];
          float dist = __builtin_amdgcn_sqrtf(fmaxf(d2, EPSF));
          __builtin_nontemporal_store(__expf(-dist), op + j * 16);
        }
      }
    }
  }
}

// ---------------- stage 4a: scale pass (bf16 sim -> f32 out), rsinv computed in-block ----------------
__global__ __launch_bounds__(256) void k_scale(const unsigned short* __restrict__ simU,
                                               const float* __restrict__ psum,
                                               float* __restrict__ out) {
  const int row = blockIdx.x;
  const size_t base = (size_t)row * 4096;
  const int tid = threadIdx.x;
  __shared__ float srow;
  if (tid < 32) {
    float s = psum[(size_t)row * 32 + tid];  // coalesced 128B
#pragma unroll
    for (int o = 16; o > 0; o >>= 1) s += __shfl_down(s, o, 64);
    if (tid == 0) srow = 1.0f / fmaxf(s, EPSF);
  }
  __syncthreads();
  const float rsv = srow;
#pragma unroll
  for (int i = 0; i < 4; ++i) {
    ushort4 v = *(const ushort4*)(simU + base + (size_t)(tid * 4 + i * 1024));
    f32x4 r;
    r[0] = bf16_to_f32(v.x) * rsv;
    r[1] = bf16_to_f32(v.y) * rsv;
    r[2] = bf16_to_f32(v.z) * rsv;
    r[3] = bf16_to_f32(v.w) * rsv;
    __builtin_nontemporal_store(r, (f32x4*)(out + base + (size_t)(tid * 4 + i * 1024)));
  }
}

// ---------------- stage 4b: fallback in-place f32 normalize ----------------
__global__ __launch_bounds__(256) void k_norm(float* __restrict__ out) {
  const size_t base = (size_t)blockIdx.x * 4096;
  const int tid = threadIdx.x;
  float4 v[4];
  float s = 0.f;
#pragma unroll
  for (int i = 0; i < 4; ++i) {
    v[i] = *(const float4*)(out + base + (size_t)(tid * 4 + i * 1024));
    s += v[i].x + v[i].y + v[i].z + v[i].w;
  }
#pragma unroll
  for (int o = 32; o > 0; o >>= 1) s += __shfl_down(s, o, 64);
  __shared__ float ws4[4];
  if ((tid & 63) == 0) ws4[tid >> 6] = s;
  __syncthreads();
  if (tid == 0) ws4[0] = ws4[0] + ws4[1] + ws4[2] + ws4[3];
  __syncthreads();
  const float inv = 1.0f / fmaxf(ws4[0], EPSF);
#pragma unroll
  for (int i = 0; i < 4; ++i) {
    f32x4 r;
    r[0] = v[i].x * inv;
    r[1] = v[i].y * inv;
    r[2] = v[i].z * inv;
    r[3] = v[i].w * inv;
    __builtin_nontemporal_store(r, (f32x4*)(out + base + (size_t)(tid * 4 + i * 1024)));
  }
}

extern "C" void kernel_launch(void* const* d_in, const int* in_sizes, int n_in,
                              void* d_out, int out_size, void* d_ws, size_t ws_size,
                              hipStream_t stream) {
  const float* m = (const float*)d_in[0];        // [4096,32,512]
  const float* om = (const float*)d_in[1];       // [32,256,512]
  const int* src_mask = (const int*)d_in[2];     // [4096,1,32]
  const int* tgt_mask = (const int*)d_in[3];     // [32,256,256]
  float* out = (float*)d_out;                    // [32,256,4096]

  float* ws = (float*)d_ws;
  float* ssq = ws;                                         // 4096 f32
  float* tsqp = ssq + 4096;                                // 4*8192 f32 partials
  float* psum = tsqp + 4 * 8192;                           // 8192*32 f32 (1 MB)
  unsigned short* srcRb = (unsigned short*)(psum + 32 * 8192);  // 4096*512 bf16
  unsigned short* Afrag = srcRb + 4096 * 512;                   // 8192*512 bf16 frag-order
  unsigned short* simU = Afrag + (size_t)8192 * 512;            // 8192*4096 bf16 (67 MB)

  const size_t need = ((size_t)4096 + 4 * 8192 + 32 * 8192) * 4 +
                      ((size_t)4096 * 512 + (size_t)8192 * 512) * 2 +
                      (size_t)8192 * 4096 * 2;
  const bool bf16_path = ws_size >= need;

  k_readouts<<<1280, 512, 0, stream>>>(m, src_mask, srcRb, ssq, om, tgt_mask, Afrag, tsqp);
  if (bf16_path) {
    k_cross_mfma<1><<<512, 1024, 0, stream>>>(Afrag, srcRb, tsqp, ssq, simU, psum, out);
    k_scale<<<8192, 256, 0, stream>>>(simU, psum, out);
  } else {
    k_cross_mfma<0><<<512, 1024, 0, stream>>>(Afrag, srcRb, tsqp, ssq, simU, psum, out);
    k_norm<<<8192, 256, 0, stream>>>(out);
  }
}

// Round 20
// 137.326 us; speedup vs baseline: 1.0134x; 1.0134x over previous
//
#include <hip/hip_runtime.h>
#include <math.h>

#define EPSF 1e-12f

typedef short bf16x8 __attribute__((ext_vector_type(8)));
typedef float f32x4 __attribute__((ext_vector_type(4)));

__device__ __forceinline__ void gload_lds16(const void* g, void* l) {
  __builtin_amdgcn_global_load_lds(
      (const __attribute__((address_space(1))) unsigned int*)g,
      (__attribute__((address_space(3))) unsigned int*)l, 16, 0, 0);
}

__device__ __forceinline__ unsigned short bf16_rne(float f) {
  unsigned int u = __float_as_uint(f);
  u += 0x7fffu + ((u >> 16) & 1u);
  return (unsigned short)(u >> 16);
}

__device__ __forceinline__ float bf16_to_f32(unsigned short h) {
  return __uint_as_float((unsigned int)h << 16);
}

// ---------------- stage 1+2 FUSED: tgt readout (blocks 0..255) + src readout (256..1279) ----------------
// tgt path also emits row-sq partials tsqp[dq][row] (squares of the rounded values,
// butterfly over the 4 replicated lane-groups) — no separate rowsq kernel.
#define WST 72
#define SMEM_BYTES 39424  // tgt path: Wb 18432 + omT 18432 + cntp 2048 + cnt_inv 512
__global__ __launch_bounds__(512) void k_readouts(
    const float* __restrict__ m, const int* __restrict__ src_mask,
    unsigned short* __restrict__ srcRb, float* __restrict__ ssq,
    const float* __restrict__ om, const int* __restrict__ tgt_mask,
    unsigned short* __restrict__ Afrag, float* __restrict__ tsqp) {
  __shared__ __attribute__((aligned(16))) char smem_raw[SMEM_BYTES];
  const int tid = threadIdx.x;

  if (blockIdx.x < 256) {
    // ---------------- tgt path ----------------
    const int b = blockIdx.x >> 3, dq = (blockIdx.x >> 1) & 3, th = blockIdx.x & 1;
    const int d0 = dq * 128, t0 = th * 128;
    unsigned short* Wb = (unsigned short*)smem_raw;
    unsigned short* omT = (unsigned short*)(smem_raw + 18432);
    float* cntp = (float*)(smem_raw + 36864);
    float* cnt_inv = (float*)(smem_raw + 38912);
    const int lane = tid & 63, w = tid >> 6;
    const int* mbase = tgt_mask + (size_t)b * 65536 + (size_t)t0 * 256;

    {
      const int t = tid >> 2, q = tid & 3;
      const int* mp = mbase + t * 256 + q * 64;
      int c = 0;
#pragma unroll
      for (int k = 0; k < 16; ++k) {
        int4 v = *(const int4*)(mp + 4 * k);
        c += v.x + v.y + v.z + v.w;
      }
      cntp[t * 4 + q] = (float)c;
    }
    __syncthreads();
    if (tid < 128) {
      float c = cntp[tid * 4] + cntp[tid * 4 + 1] + cntp[tid * 4 + 2] + cntp[tid * 4 + 3];
      cnt_inv[tid] = 1.0f / fmaxf(c, EPSF);
    }

    f32x4 acc[8];
#pragma unroll
    for (int di = 0; di < 8; ++di) acc[di] = (f32x4){0.f, 0.f, 0.f, 0.f};

    for (int uc = 0; uc < 4; ++uc) {
      const int ub = uc * 64;
      __syncthreads();
      {
        const int t = tid >> 2, ul0 = (tid & 3) * 16;
        const int* mp = mbase + t * 256 + ub + ul0;
        unsigned short* wp = Wb + t * WST + ul0;
#pragma unroll
        for (int k = 0; k < 4; ++k) {
          int4 v = *(const int4*)(mp + 4 * k);
          ushort4 h;
          h.x = v.x ? 0x3F80 : 0;
          h.y = v.y ? 0x3F80 : 0;
          h.z = v.z ? 0x3F80 : 0;
          h.w = v.w ? 0x3F80 : 0;
          *(ushort4*)(wp + 4 * k) = h;
        }
      }
      {
#pragma unroll
        for (int k = 0; k < 4; ++k) {
          const int idx = tid + 512 * k;
          const int u = idx >> 5, dl = (idx & 31) * 4;
          float4 v = *(const float4*)(om + (size_t)b * 131072 + (size_t)(ub + u) * 512 + d0 + dl);
          omT[(dl + 0) * WST + u] = bf16_rne(v.x);
          omT[(dl + 1) * WST + u] = bf16_rne(v.y);
          omT[(dl + 2) * WST + u] = bf16_rne(v.z);
          omT[(dl + 3) * WST + u] = bf16_rne(v.w);
        }
      }
      __syncthreads();
#pragma unroll
      for (int kt2 = 0; kt2 < 2; ++kt2) {
        const int ko = kt2 * 32 + (lane >> 4) * 8;
        bf16x8 wf = *(const bf16x8*)(Wb + (w * 16 + (lane & 15)) * WST + ko);
        bf16x8 of[8];
#pragma unroll
        for (int di = 0; di < 8; ++di)
          of[di] = *(const bf16x8*)(omT + (di * 16 + (lane & 15)) * WST + ko);
#pragma unroll
        for (int di = 0; di < 8; ++di)
          acc[di] = __builtin_amdgcn_mfma_f32_16x16x32_bf16(of[di], wf, acc[di], 0, 0, 0);
      }
    }

    const int tl = w * 16 + (lane & 15);
    const int rT = b * 256 + t0 + tl;
    const float inv = cnt_inv[tl];
    float sq = 0.f;
#pragma unroll
    for (int di = 0; di < 8; ++di) {
      const int d = d0 + di * 16 + (lane >> 4) * 4;
      ushort4 o;
      o.x = bf16_rne(acc[di][0] * inv);
      o.y = bf16_rne(acc[di][1] * inv);
      o.z = bf16_rne(acc[di][2] * inv);
      o.w = bf16_rne(acc[di][3] * inv);
      float fx = bf16_to_f32(o.x), fy = bf16_to_f32(o.y);
      float fz = bf16_to_f32(o.z), fw = bf16_to_f32(o.w);
      sq += fx * fx + fy * fy + fz * fz + fw * fw;
      const size_t off =
          (((size_t)(rT >> 4) * 16 + (d >> 5)) * 64 + ((d >> 3) & 3) * 16 + (rT & 15)) * 8 + (d & 7);
      *(ushort4*)(Afrag + off) = o;
    }
    sq += __shfl_xor(sq, 16, 64);
    sq += __shfl_xor(sq, 32, 64);
    if ((lane >> 4) == 0) tsqp[(size_t)dq * 8192 + rT] = sq;
  } else {
    // ---------------- src path: 4 batches per block ----------------
    const int sid = blockIdx.x - 256;
    const int sub = tid >> 7, t = tid & 127;
    const int b = sid * 4 + sub;
    int* msk = (int*)smem_raw;            // [4][32]
    float* sinv = (float*)(smem_raw + 512);
    float* red = (float*)(smem_raw + 528);  // [8]
    if (t < 32) msk[sub * 32 + t] = src_mask[b * 32 + t];
    __syncthreads();
    if (t == 0) {
      float c = 0.f;
      for (int s = 0; s < 32; ++s) c += (float)msk[sub * 32 + s];
      sinv[sub] = 1.0f / fmaxf(c, EPSF);
    }
    __syncthreads();
    const float inv = sinv[sub];
    const float4* mb = (const float4*)(m + (size_t)b * (32 * 512)) + t;
    float ax = 0.f, ay = 0.f, az = 0.f, aw = 0.f;
    for (int s = 0; s < 32; ++s) {
      if (msk[sub * 32 + s] != 0) {
        float4 v = mb[s * 128];
        ax += v.x; ay += v.y; az += v.z; aw += v.w;
      }
    }
    ushort4 o;
    o.x = bf16_rne(ax * inv);
    o.y = bf16_rne(ay * inv);
    o.z = bf16_rne(az * inv);
    o.w = bf16_rne(aw * inv);
    *(ushort4*)(srcRb + (size_t)b * 512 + t * 4) = o;
    float fx = bf16_to_f32(o.x), fy = bf16_to_f32(o.y);
    float fz = bf16_to_f32(o.z), fw = bf16_to_f32(o.w);
    float s = fx * fx + fy * fy + fz * fz + fw * fw;
#pragma unroll
    for (int oo = 32; oo > 0; oo >>= 1) s += __shfl_down(s, oo, 64);
    if ((tid & 63) == 0) red[tid >> 6] = s;
    __syncthreads();
    if (t == 0) ssq[b] = red[sub * 2] + red[sub * 2 + 1];
  }
}

// ---------------- stage 3: cross GEMM — 16 waves, bf16 sim + in-kernel row psums ----------------
// tsq is read as the sum of the 4 d-quarter partials tsqp[0..3][row].
template <int BF16SIM>
__global__ __launch_bounds__(1024, 4) void k_cross_mfma(
    const unsigned short* __restrict__ Afrag, const unsigned short* __restrict__ B,
    const float* __restrict__ tsqp, const float* __restrict__ ssq,
    unsigned short* __restrict__ simU, float* __restrict__ psum,
    float* __restrict__ outF) {
  __shared__ unsigned short Bs[128 * 512];
  const int tid = threadIdx.x;
  const int lane = tid & 63, w = tid >> 6;  // 16 waves
  const int bid = blockIdx.x;
  const int xcd = bid & 7, idx = bid >> 3;
  const int row0 = (xcd * 2 + (idx >> 5)) * 512;
  const int col0 = (idx & 31) * 128;
  const int lr = lane & 15, lkh = lane >> 4;

  // stage B once: 128 chunks of 1KB, 8 per wave
#pragma unroll
  for (int t = 0; t < 8; ++t) {
    const int c = w * 8 + t;
    const int j = c >> 4, kt = c & 15;
    gload_lds16(B + (size_t)(col0 + j * 16 + lr) * 512 + kt * 32 + lkh * 8,
                Bs + (size_t)c * 512);
  }

  f32x4 acc[2][8];
#pragma unroll
  for (int i = 0; i < 2; ++i)
#pragma unroll
    for (int j = 0; j < 8; ++j) acc[i][j] = (f32x4){0.f, 0.f, 0.f, 0.f};

  __syncthreads();

  // wave tile: 32 rows (2 row-blocks of 16) x 128 cols
  const unsigned short* ap = Afrag + ((size_t)(row0 >> 4) + w * 2) * (16 * 64 * 8);
#pragma unroll
  for (int kt = 0; kt < 16; ++kt) {
    bf16x8 af[2], bfr[8];
#pragma unroll
    for (int i = 0; i < 2; ++i)
      af[i] = *(const bf16x8*)(ap + (((size_t)i * 16 + kt) * 64 + lane) * 8);
#pragma unroll
    for (int j = 0; j < 8; ++j)
      bfr[j] = *(const bf16x8*)(Bs + ((j * 16 + kt) * 64 + lane) * 8);
#pragma unroll
    for (int i = 0; i < 2; ++i)
#pragma unroll
      for (int j = 0; j < 8; ++j)
        acc[i][j] = __builtin_amdgcn_mfma_f32_16x16x32_bf16(af[i], bfr[j], acc[i][j], 0, 0, 0);
  }

  const int cbase = col0 + (lane & 15);
  const int rbase = row0 + w * 32 + (lane >> 4) * 4;
  float ss[8];
#pragma unroll
  for (int j = 0; j < 8; ++j) ss[j] = ssq[cbase + j * 16];
#pragma unroll
  for (int i = 0; i < 2; ++i) {
#pragma unroll
    for (int r = 0; r < 4; ++r) {
      const int row = rbase + i * 16 + r;
      const float t2 = tsqp[row] + tsqp[8192 + row] + tsqp[2 * 8192 + row] + tsqp[3 * 8192 + row];
      if (BF16SIM) {
        unsigned short* sp = simU + (size_t)row * 4096 + cbase;
        float s = 0.f;
#pragma unroll
        for (int j = 0; j < 8; ++j) {
          float d2 = t2 + ss[j] - 2.0f * acc[i][j][r];
          float sim = __expf(-__builtin_amdgcn_sqrtf(fmaxf(d2, EPSF)));
          s += sim;
          __builtin_nontemporal_store(bf16_rne(sim), sp + j * 16);
        }
        s += __shfl_xor(s, 1, 64);
        s += __shfl_xor(s, 2, 64);
        s += __shfl_xor(s, 4, 64);
        s += __shfl_xor(s, 8, 64);
        if ((lane & 15) == 0) psum[(size_t)row * 32 + (col0 >> 7)] = s;
      } else {
        float* op = outF + (size_t)row * 4096 + cbase;
#pragma unroll
        for (int j = 0; j < 8; ++j) {
          float d2 = t2 + ss[j] - 2.0f * acc[i][j][r];
          float dist = __builtin_amdgcn_sqrtf(fmaxf(d2, EPSF));
          __builtin_nontemporal_store(__expf(-dist), op + j * 16);
        }
      }
    }
  }
}

// ---------------- stage 4a: scale pass (bf16 sim -> f32 out), rsinv computed in-block ----------------
__global__ __launch_bounds__(256) void k_scale(const unsigned short* __restrict__ simU,
                                               const float* __restrict__ psum,
                                               float* __restrict__ out) {
  const int row = blockIdx.x;
  const size_t base = (size_t)row * 4096;
  const int tid = threadIdx.x;
  __shared__ float srow;
  if (tid < 32) {
    float s = psum[(size_t)row * 32 + tid];  // coalesced 128B
#pragma unroll
    for (int o = 16; o > 0; o >>= 1) s += __shfl_down(s, o, 64);
    if (tid == 0) srow = 1.0f / fmaxf(s, EPSF);
  }
  __syncthreads();
  const float rsv = srow;
#pragma unroll
  for (int i = 0; i < 4; ++i) {
    ushort4 v = *(const ushort4*)(simU + base + (size_t)(tid * 4 + i * 1024));
    f32x4 r;
    r[0] = bf16_to_f32(v.x) * rsv;
    r[1] = bf16_to_f32(v.y) * rsv;
    r[2] = bf16_to_f32(v.z) * rsv;
    r[3] = bf16_to_f32(v.w) * rsv;
    __builtin_nontemporal_store(r, (f32x4*)(out + base + (size_t)(tid * 4 + i * 1024)));
  }
}

// ---------------- stage 4b: fallback in-place f32 normalize ----------------
__global__ __launch_bounds__(256) void k_norm(float* __restrict__ out) {
  const size_t base = (size_t)blockIdx.x * 4096;
  const int tid = threadIdx.x;
  float4 v[4];
  float s = 0.f;
#pragma unroll
  for (int i = 0; i < 4; ++i) {
    v[i] = *(const float4*)(out + base + (size_t)(tid * 4 + i * 1024));
    s += v[i].x + v[i].y + v[i].z + v[i].w;
  }
#pragma unroll
  for (int o = 32; o > 0; o >>= 1) s += __shfl_down(s, o, 64);
  __shared__ float ws4[4];
  if ((tid & 63) == 0) ws4[tid >> 6] = s;
  __syncthreads();
  if (tid == 0) ws4[0] = ws4[0] + ws4[1] + ws4[2] + ws4[3];
  __syncthreads();
  const float inv = 1.0f / fmaxf(ws4[0], EPSF);
#pragma unroll
  for (int i = 0; i < 4; ++i) {
    f32x4 r;
    r[0] = v[i].x * inv;
    r[1] = v[i].y * inv;
    r[2] = v[i].z * inv;
    r[3] = v[i].w * inv;
    __builtin_nontemporal_store(r, (f32x4*)(out + base + (size_t)(tid * 4 + i * 1024)));
  }
}

extern "C" void kernel_launch(void* const* d_in, const int* in_sizes, int n_in,
                              void* d_out, int out_size, void* d_ws, size_t ws_size,
                              hipStream_t stream) {
  const float* m = (const float*)d_in[0];        // [4096,32,512]
  const float* om = (const float*)d_in[1];       // [32,256,512]
  const int* src_mask = (const int*)d_in[2];     // [4096,1,32]
  const int* tgt_mask = (const int*)d_in[3];     // [32,256,256]
  float* out = (float*)d_out;                    // [32,256,4096]

  float* ws = (float*)d_ws;
  float* ssq = ws;                                         // 4096 f32
  float* tsqp = ssq + 4096;                                // 4*8192 f32 partials
  float* psum = tsqp + 4 * 8192;                           // 8192*32 f32 (1 MB)
  unsigned short* srcRb = (unsigned short*)(psum + 32 * 8192);  // 4096*512 bf16
  unsigned short* Afrag = srcRb + 4096 * 512;                   // 8192*512 bf16 frag-order
  unsigned short* simU = Afrag + (size_t)8192 * 512;            // 8192*4096 bf16 (67 MB)

  const size_t need = ((size_t)4096 + 4 * 8192 + 32 * 8192) * 4 +
                      ((size_t)4096 * 512 + (size_t)8192 * 512) * 2 +
                      (size_t)8192 * 4096 * 2;
  const bool bf16_path = ws_size >= need;

  k_readouts<<<1280, 512, 0, stream>>>(m, src_mask, srcRb, ssq, om, tgt_mask, Afrag, tsqp);
  if (bf16_path) {
    k_cross_mfma<1><<<512, 1024, 0, stream>>>(Afrag, srcRb, tsqp, ssq, simU, psum, out);
    k_scale<<<8192, 256, 0, stream>>>(simU, psum, out);
  } else {
    k_cross_mfma<0><<<512, 1024, 0, stream>>>(Afrag, srcRb, tsqp, ssq, simU, psum, out);
    k_norm<<<8192, 256, 0, stream>>>(out);
  }
}